// Round 4
// baseline (1600.872 us; speedup 1.0000x reference)
//
#include <hip/hip_runtime.h>
#include <hip/hip_cooperative_groups.h>
#include <stdint.h>

namespace cg = cooperative_groups;

// =====================================================================
// Gps fused pipeline, single cooperative kernel (MI355X / gfx950).
//
//   P0 : prep  — split/transpose W1/W2 quadrants into blocked bf16-pair
//   P1 : G1 = (f1@W1b^T)*.5 -> B1[0:4096); G2 = (f2@W2b^T)*.5 -> B2[0:2048)
//   P2 : K2 partials: [adj1 | gather(featm,seed)] @ B1, K split in 2 -> P0/P1
//   P2b: h = lrelu(P0+P1) -> split pair (Hh,Hl)
//   P3 : K3 partials: [mean4(adj2) | h] @ B2, K split in 2 -> P0/P1 (reused)
//   P3b: out = lrelu(P0+P1)
//
// GEMM: BM=128 x BN=256, 8 waves (2Mx4N), wave tile 64x64, BK=32,
// triple-split bf16 MFMA (hh, lh, hl) ~ 1e-5 rel err. 2-phase dbuf LDS,
// B via global_load_lds(16B), A via reg-staged load-early/write-late.
// =====================================================================

typedef unsigned short u16;
typedef unsigned int   u32;
typedef __attribute__((ext_vector_type(8))) short bf16x8;
typedef __attribute__((ext_vector_type(4))) float f32x4;
typedef __attribute__((ext_vector_type(4))) u16   u16x4;
typedef __attribute__((ext_vector_type(8))) u16   u16x8;

#define DEVI __device__ __forceinline__

constexpr int BM = 128, BN = 256, BK = 32;
constexpr int NTHR = 512;

DEVI u16 f2bf(float f) {                       // RTNE f32 -> bf16 bits
  union { float f; u32 u; } v; v.f = f;
  return (u16)((v.u + 0x7fffu + ((v.u >> 16) & 1u)) >> 16);
}
DEVI float bf2f(u16 h) {
  union { u32 u; float f; } v; v.u = ((u32)h) << 16; return v.f;
}
DEVI void split2(float x, u16& hi, u16& lo) {  // x ~= hi + lo
  hi = f2bf(x);
  lo = f2bf(x - bf2f(hi));
}

DEVI void gll16(const u16* g, u16* l) {        // async global->LDS, 16B/lane
  __builtin_amdgcn_global_load_lds(
      (__attribute__((address_space(1))) u32*)g,
      (__attribute__((address_space(3))) u32*)l, 16, 0, 0);
}

// ---------------- A staging (load-early / write-late) ----------------
// thread t: kb = t>>7 (k-block 0..3), row = t&127; stages A[row][kb*8..+8)
struct ARegs { f32x4 r0,r1,r2,r3,r4,r5,r6,r7; u16x4 h0,h1,l0,l1; };

template<int MODE>
DEVI void loadA(const float* __restrict__ A1, int lda1,
                const float* __restrict__ featm, const int* __restrict__ seed,
                const u16* __restrict__ A3h, const u16* __restrict__ A3l,
                int tileM, int kk, int row, ARegs& a)
{
  if constexpr (MODE == 0) {          // plain fp32 rows
    const float* p = &A1[(size_t)(tileM + row) * lda1 + kk];
    a.r0 = *(const f32x4*)p; a.r1 = *(const f32x4*)(p + 4);
  } else if constexpr (MODE == 1) {   // gathered feature rows
    const int s = seed[tileM + row];
    const float* p = &featm[(size_t)s * 256 + kk];
    a.r0 = *(const f32x4*)p; a.r1 = *(const f32x4*)(p + 4);
  } else if constexpr (MODE == 2) {   // mean of 4 consecutive rows
    const float* p = &A1[(size_t)(tileM + row) * 4 * lda1 + kk];
    a.r0 = *(const f32x4*)p;              a.r4 = *(const f32x4*)(p + 4);
    a.r1 = *(const f32x4*)(p + lda1);     a.r5 = *(const f32x4*)(p + lda1 + 4);
    a.r2 = *(const f32x4*)(p + 2*lda1);   a.r6 = *(const f32x4*)(p + 2*lda1 + 4);
    a.r3 = *(const f32x4*)(p + 3*lda1);   a.r7 = *(const f32x4*)(p + 3*lda1 + 4);
  } else {                            // pre-split pair passthrough
    const size_t o = (size_t)(tileM + row) * 256 + kk;
    a.h0 = *(const u16x4*)&A3h[o]; a.h1 = *(const u16x4*)&A3h[o + 4];
    a.l0 = *(const u16x4*)&A3l[o]; a.l1 = *(const u16x4*)&A3l[o + 4];
  }
}

template<int MODE>
DEVI void writeA(ARegs& a, u16* dh, u16* dl)
{
  u16x8 h, l;
  if constexpr (MODE == 3) {
#pragma unroll
    for (int j = 0; j < 4; ++j) {
      h[j] = a.h0[j]; h[4 + j] = a.h1[j];
      l[j] = a.l0[j]; l[4 + j] = a.l1[j];
    }
  } else {
    f32x4 e0 = a.r0, e1 = a.r1;
    if constexpr (MODE == 2) {
      e0 = (a.r0 + a.r1 + a.r2 + a.r3) * 0.25f;
      e1 = (a.r4 + a.r5 + a.r6 + a.r7) * 0.25f;
    }
#pragma unroll
    for (int j = 0; j < 4; ++j) {
      u16 x, y;
      split2(e0[j], x, y); h[j] = x;     l[j] = y;
      split2(e1[j], x, y); h[4 + j] = x; l[4 + j] = y;
    }
  }
  *(u16x8*)dh = h;
  *(u16x8*)dl = l;
}

// B tile for step s is a contiguous 16KB (per hi/lo) chunk of the blocked
// array: [kb 0..3][n 0..255][8] -> global_load_lds straight copy.
DEVI void stageB(const u16* __restrict__ Bh, const u16* __restrict__ Bl,
                 int s, u16* dBh, u16* dBl, int tid)
{
  const size_t base = (size_t)s * (BK * BN);
  const int wv = tid >> 6, ln = tid & 63;
#pragma unroll
  for (int c = 0; c < 2; ++c) {
    const int lo = c * 4096 + wv * 512;       // wave-uniform LDS offset
    gll16(Bh + base + lo + ln * 8, dBh + lo);
    gll16(Bl + base + lo + ln * 8, dBl + lo);
  }
}

// ---------------------------------------------------------------------
// C tile 128x256 per block. Global K-steps [s0,s1); A mode = AM1 below
// ssplit, AM2 (k rebased) at/after. OM: 0 = *0.5 + split-store blocked
// (G into B arrays); 3 = raw fp32 partial store.
// ---------------------------------------------------------------------
template<int AM1, int AM2, int OM>
DEVI void gemm_dev(u16 (&sA)[2][2][BM*BK], u16 (&sB)[2][2][BK*BN],
                   int tileM, int s0, int s1, int ssplit,
                   const float* __restrict__ A1, int lda1,
                   const float* __restrict__ featm, const int* __restrict__ seed,
                   const u16* __restrict__ A3h, const u16* __restrict__ A3l,
                   const u16* __restrict__ Bh, const u16* __restrict__ Bl,
                   float* __restrict__ Of, u16* __restrict__ Oh, u16* __restrict__ Ol)
{
  const int tid  = threadIdx.x;
  const int lane = tid & 63, wave = tid >> 6;
  const int wm = wave >> 2, wn = wave & 3;      // 2 (M) x 4 (N)
  const int l15 = lane & 15, l4 = lane >> 4;
  const int kb = tid >> 7, row = tid & 127;     // staging ownership

  f32x4 acc[4][4] = {};

  { // prologue: stage step s0 into buffer 0
    stageB(Bh, Bl, s0, sB[0][0], sB[0][1], tid);
    ARegs a;
    const bool m1 = s0 < ssplit;
    const int kk = (m1 ? s0 * BK : (s0 - ssplit) * BK) + kb * 8;
    if (m1) loadA<AM1>(A1, lda1, featm, seed, A3h, A3l, tileM, kk, row, a);
    else    loadA<AM2>(A1, lda1, featm, seed, A3h, A3l, tileM, kk, row, a);
    u16* dh = &sA[0][0][(kb * BM + row) * 8];
    u16* dl = &sA[0][1][(kb * BM + row) * 8];
    if (m1) writeA<AM1>(a, dh, dl); else writeA<AM2>(a, dh, dl);
  }
  __syncthreads();

  for (int s = s0; s < s1; ++s) {
    const int  cur = (s - s0) & 1, nb = cur ^ 1;
    const bool hn  = (s + 1) < s1;

    // issue next-step staging early (B async->LDS, A global->regs)
    ARegs a; bool m1 = true;
    if (hn) {
      stageB(Bh, Bl, s + 1, sB[nb][0], sB[nb][1], tid);
      m1 = (s + 1) < ssplit;
      const int kk = (m1 ? (s + 1) * BK : (s + 1 - ssplit) * BK) + kb * 8;
      if (m1) loadA<AM1>(A1, lda1, featm, seed, A3h, A3l, tileM, kk, row, a);
      else    loadA<AM2>(A1, lda1, featm, seed, A3h, A3l, tileM, kk, row, a);
    }

    // compute current buffer: wave tile 64x64, triple-split
    bf16x8 ah[4], al[4], bh[4], bl[4];
#pragma unroll
    for (int mf = 0; mf < 4; ++mf) {
      const int sa = (l4 * BM + wm * 64 + mf * 16 + l15) * 8;
      ah[mf] = *(const bf16x8*)&sA[cur][0][sa];
      al[mf] = *(const bf16x8*)&sA[cur][1][sa];
    }
#pragma unroll
    for (int nf = 0; nf < 4; ++nf) {
      const int sb = (l4 * BN + wn * 64 + nf * 16 + l15) * 8;
      bh[nf] = *(const bf16x8*)&sB[cur][0][sb];
      bl[nf] = *(const bf16x8*)&sB[cur][1][sb];
    }
#pragma unroll
    for (int mf = 0; mf < 4; ++mf)
#pragma unroll
      for (int nf = 0; nf < 4; ++nf) {
        acc[mf][nf] = __builtin_amdgcn_mfma_f32_16x16x32_bf16(ah[mf], bh[nf], acc[mf][nf], 0, 0, 0);
        acc[mf][nf] = __builtin_amdgcn_mfma_f32_16x16x32_bf16(al[mf], bh[nf], acc[mf][nf], 0, 0, 0);
        acc[mf][nf] = __builtin_amdgcn_mfma_f32_16x16x32_bf16(ah[mf], bl[nf], acc[mf][nf], 0, 0, 0);
      }

    // write-late: convert + LDS write (global loads hid under MFMAs)
    if (hn) {
      u16* dh = &sA[nb][0][(kb * BM + row) * 8];
      u16* dl = &sA[nb][1][(kb * BM + row) * 8];
      if (m1) writeA<AM1>(a, dh, dl); else writeA<AM2>(a, dh, dl);
    }
    __syncthreads();
  }

  // epilogue. C/D frag: col = lane&15, row = (lane>>4)*4 + reg (m89)
#pragma unroll
  for (int mf = 0; mf < 4; ++mf)
#pragma unroll
    for (int nf = 0; nf < 4; ++nf)
#pragma unroll
      for (int j = 0; j < 4; ++j) {
        const int r = tileM + wm * 64 + mf * 16 + l4 * 4 + j;
        const int c = wn * 64 + nf * 16 + l15;
        float v = acc[mf][nf][j];
        if constexpr (OM == 0) {
          v *= 0.5f;
          u16 hi, lo; split2(v, hi, lo);
          const size_t o = ((size_t)(r >> 3) * 256 + c) * 8 + (r & 7);
          Oh[o] = hi; Ol[o] = lo;
        } else {
          Of[(size_t)r * 256 + c] = v;
        }
      }
}

// ---------------------------------------------------------------------
struct GpsP {
  const float *featm, *adj1, *f1, *adj2, *f2, *W1, *W2;
  const int* seed;
  float* out;
  u16 *B1h, *B1l, *B2h, *B2l, *Wt1h, *Wt1l, *Wt2h, *Wt2l, *Hh, *Hl;
  float *P0, *P1;
};

__global__ __launch_bounds__(512, 2) void gps_fused(GpsP p)
{
  __shared__ u16 sA[2][2][BM*BK];   // 32 KB
  __shared__ u16 sB[2][2][BK*BN];   // 64 KB
  cg::grid_group grid = cg::this_grid();
  const int bid = blockIdx.x, tid = threadIdx.x;
  const int t0 = bid * NTHR + tid;

  // ---- P0: weight prep (4 jobs x 65536 items = 2 per thread)
#pragma unroll
  for (int rep = 0; rep < 2; ++rep) {
    const int idx = rep * 131072 + t0;
    const int job = idx >> 16, e = idx & 65535, n = e >> 8, k = e & 255;
    u16 hi, lo;
    if (job == 0) {        // Wt1 = W1b^T (blocked)
      split2(p.W1[n * 512 + 256 + k], hi, lo);
      const int o = ((k >> 3) * 256 + n) * 8 + (k & 7);
      p.Wt1h[o] = hi; p.Wt1l[o] = lo;
    } else if (job == 1) { // B1 tail rows 4096+k = W1a^T
      split2(p.W1[n * 512 + k], hi, lo);
      const int r = 4096 + k;
      const size_t o = ((size_t)(r >> 3) * 256 + n) * 8 + (r & 7);
      p.B1h[o] = hi; p.B1l[o] = lo;
    } else if (job == 2) { // Wt2 = W2b^T
      split2(p.W2[n * 512 + 256 + k], hi, lo);
      const int o = ((k >> 3) * 256 + n) * 8 + (k & 7);
      p.Wt2h[o] = hi; p.Wt2l[o] = lo;
    } else {               // B2 tail rows 2048+k = W2a^T
      split2(p.W2[n * 512 + k], hi, lo);
      const int r = 2048 + k;
      const size_t o = ((size_t)(r >> 3) * 256 + n) * 8 + (r & 7);
      p.B2h[o] = hi; p.B2l[o] = lo;
    }
  }
  __threadfence(); grid.sync();

  // ---- P1: G1 (blocks 0-31), G2 (blocks 32-47)
  if (bid < 32)
    gemm_dev<0,0,0>(sA, sB, bid * BM, 0, 8, 8,
                    p.f1, 256, nullptr, nullptr, nullptr, nullptr,
                    p.Wt1h, p.Wt1l, nullptr, p.B1h, p.B1l);
  else if (bid < 48)
    gemm_dev<0,0,0>(sA, sB, (bid - 32) * BM, 0, 8, 8,
                    p.f2, 256, nullptr, nullptr, nullptr, nullptr,
                    p.Wt2h, p.Wt2l, nullptr, p.B2h, p.B2l);
  __threadfence(); grid.sync();

  // ---- P2: layer-1 GEMM partials, K=4352 (136 steps) split in 2 groups
  {
    const int g = bid >> 7, tile = bid & 127;
    gemm_dev<0,1,3>(sA, sB, tile * BM, g * 68, (g + 1) * 68, 128,
                    p.adj1, 4096, p.featm, p.seed, nullptr, nullptr,
                    p.B1h, p.B1l, g ? p.P1 : p.P0, nullptr, nullptr);
  }
  __threadfence(); grid.sync();

  // ---- P2b: h = lrelu(P0+P1) -> split pair
#pragma unroll
  for (int rep = 0; rep < 8; ++rep) {
    const int idx = rep * 131072 + t0;      // f32x4 index, 1048576 total
    f32x4 v = ((const f32x4*)p.P0)[idx] + ((const f32x4*)p.P1)[idx];
    u16x4 h, l;
#pragma unroll
    for (int j = 0; j < 4; ++j) {
      float x = v[j]; x = x >= 0.f ? x : 0.01f * x;
      u16 a, b; split2(x, a, b); h[j] = a; l[j] = b;
    }
    ((u16x4*)p.Hh)[idx] = h; ((u16x4*)p.Hl)[idx] = l;
  }
  __threadfence(); grid.sync();

  // ---- P3: layer-2 GEMM partials, K=2304 (72 steps) split in 2 groups
  {
    const int g = bid >> 7, tile = bid & 127;
    gemm_dev<2,3,3>(sA, sB, tile * BM, g * 36, (g + 1) * 36, 64,
                    p.adj2, 2048, nullptr, nullptr, p.Hh, p.Hl,
                    p.B2h, p.B2l, g ? p.P1 : p.P0, nullptr, nullptr);
  }
  __threadfence(); grid.sync();

  // ---- P3b: out = lrelu(P0+P1)
#pragma unroll
  for (int rep = 0; rep < 8; ++rep) {
    const int idx = rep * 131072 + t0;
    f32x4 v = ((const f32x4*)p.P0)[idx] + ((const f32x4*)p.P1)[idx];
#pragma unroll
    for (int j = 0; j < 4; ++j) { float x = v[j]; v[j] = x >= 0.f ? x : 0.01f * x; }
    ((f32x4*)p.out)[idx] = v;
  }
}

// ---------------------------------------------------------------------
extern "C" void kernel_launch(void* const* d_in, const int* in_sizes, int n_in,
                              void* d_out, int out_size, void* d_ws, size_t ws_size,
                              hipStream_t stream)
{
  GpsP hp;
  hp.featm = (const float*)d_in[0];
  hp.adj1  = (const float*)d_in[1];
  hp.f1    = (const float*)d_in[2];
  hp.adj2  = (const float*)d_in[3];
  hp.f2    = (const float*)d_in[4];
  hp.W1    = (const float*)d_in[5];
  hp.W2    = (const float*)d_in[6];
  hp.seed  = (const int*)d_in[7];
  hp.out   = (float*)d_out;

  char* q = (char*)d_ws;
  auto take = [&](size_t bytes) { char* r = q; q += ((bytes + 255) & ~(size_t)255); return r; };
  hp.B1h  = (u16*)take((size_t)4352 * 256 * 2);
  hp.B1l  = (u16*)take((size_t)4352 * 256 * 2);
  hp.B2h  = (u16*)take((size_t)2304 * 256 * 2);
  hp.B2l  = (u16*)take((size_t)2304 * 256 * 2);
  hp.Wt1h = (u16*)take((size_t)256 * 256 * 2);
  hp.Wt1l = (u16*)take((size_t)256 * 256 * 2);
  hp.Wt2h = (u16*)take((size_t)256 * 256 * 2);
  hp.Wt2l = (u16*)take((size_t)256 * 256 * 2);
  hp.Hh   = (u16*)take((size_t)16384 * 256 * 2);
  hp.Hl   = (u16*)take((size_t)16384 * 256 * 2);
  hp.P0   = (float*)take((size_t)16384 * 256 * 4);
  hp.P1   = (float*)take((size_t)16384 * 256 * 4);

  void* args[] = { (void*)&hp };
  hipLaunchCooperativeKernel((const void*)gps_fused, dim3(256), dim3(512),
                             args, 0, stream);
}